// Round 1
// baseline (477.445 us; speedup 1.0000x reference)
//
#include <hip/hip_runtime.h>
#include <hip/hip_bf16.h>
#include <math.h>

typedef float f32x4 __attribute__((ext_vector_type(4)));

#define H_DIM   4096
#define E_EXP   64
#define NTOK    16384
#define BT      64          // tokens per block
#define BK      64          // K chunk
#define LDX     68          // padded LDS row stride (floats), 16B-aligned rows
#define NBLK    (NTOK/BT)   // 256
#define PART_STRIDE 132     // floats per block partial: 64 psum + 64 cnt + 1 z

// ---------------------------------------------------------------------------
// Main kernel: fused gate GEMM (fp32 vector FMA) + softmax + top-2 + partials
// ---------------------------------------------------------------------------
__global__ __launch_bounds__(256) void moe_gate_main(
    const float* __restrict__ x, const float* __restrict__ gw,
    const float* __restrict__ bias, float* __restrict__ out,
    float* __restrict__ part)
{
    __shared__ float xs[BT * LDX];   // x tile  [token][k]   (later: logits/probs)
    __shared__ float ws[E_EXP * LDX];// w tile  [expert][k]
    __shared__ float bs[E_EXP];
    __shared__ float rs[BT];         // per-token 1/softmax-denom
    __shared__ int   ia[BT], ib[BT]; // per-token top-2 indices

    const int tid  = threadIdx.x;
    const int bid  = blockIdx.x;
    const int tok0 = bid * BT;
    const int tx   = tid & 15;       // expert group: experts {tx + 16j}
    const int ty   = tid >> 4;       // token group:  tokens  {ty + 16i}

    if (tid < E_EXP) bs[tid] = bias[tid];

    // staging mapping: thread loads rows {srow+16i}, cols [scol, scol+4)
    const int srow = tid >> 4;
    const int scol = (tid & 15) * 4;
    const float* xp = x  + (size_t)(tok0 + srow) * H_DIM + scol;
    const float* wp = gw + (size_t)srow * H_DIM + scol;

    float acc[4][4];
#pragma unroll
    for (int i = 0; i < 4; i++)
#pragma unroll
        for (int j = 0; j < 4; j++) acc[i][j] = 0.f;

    // prefetch chunk 0 into registers
    f32x4 rx[4], rw[4];
#pragma unroll
    for (int i = 0; i < 4; i++) {
        rx[i] = *(const f32x4*)(xp + (size_t)(16 * i) * H_DIM);
        rw[i] = *(const f32x4*)(wp + (size_t)(16 * i) * H_DIM);
    }

    for (int c = 0; c < H_DIM / BK; c++) {
        __syncthreads();            // previous chunk's LDS reads done
#pragma unroll
        for (int i = 0; i < 4; i++) {
            *(f32x4*)&xs[(srow + 16 * i) * LDX + scol] = rx[i];
            *(f32x4*)&ws[(srow + 16 * i) * LDX + scol] = rw[i];
        }
        __syncthreads();
        if (c + 1 < H_DIM / BK) {   // issue next-chunk global loads, hide under FMA
            const int k0 = (c + 1) * BK;
#pragma unroll
            for (int i = 0; i < 4; i++) {
                rx[i] = *(const f32x4*)(xp + (size_t)(16 * i) * H_DIM + k0);
                rw[i] = *(const f32x4*)(wp + (size_t)(16 * i) * H_DIM + k0);
            }
        }
#pragma unroll
        for (int kk = 0; kk < BK; kk += 4) {
            f32x4 xv[4], wv[4];
#pragma unroll
            for (int i = 0; i < 4; i++) xv[i] = *(const f32x4*)&xs[(ty + 16 * i) * LDX + kk];
#pragma unroll
            for (int j = 0; j < 4; j++) wv[j] = *(const f32x4*)&ws[(tx + 16 * j) * LDX + kk];
#pragma unroll
            for (int i = 0; i < 4; i++)
#pragma unroll
                for (int j = 0; j < 4; j++)
#pragma unroll
                    for (int q = 0; q < 4; q++)
                        acc[i][j] += xv[i][q] * wv[j][q];
        }
    }

    // ---- write logits into xs[token][expert] ----
    __syncthreads();
#pragma unroll
    for (int i = 0; i < 4; i++)
#pragma unroll
        for (int j = 0; j < 4; j++)
            xs[(ty + 16 * i) * LDX + (tx + 16 * j)] = acc[i][j];
    __syncthreads();

    // ---- per-token epilogue: lanes 0..63 of wave 0, one token each ----
    float zsq = 0.f;
    if (tid < BT) {
        const float invTemp = (1.0f / 3.0f);
        float m = -1e30f, m2 = -1e30f;
        int i1 = 0, i2 = 0;
        for (int e = 0; e < E_EXP; e++) {
            float v = (xs[tid * LDX + e] + bs[e]) * invTemp;
            xs[tid * LDX + e] = v;
            if (v > m)       { m2 = m; i2 = i1; m = v; i1 = e; }
            else if (v > m2) { m2 = v; i2 = e; }
        }
        float s = 0.f;
        for (int e = 0; e < E_EXP; e++) {
            float p = expf(xs[tid * LDX + e] - m);
            xs[tid * LDX + e] = p;      // unnormalized prob
            s += p;
        }
        rs[tid] = 1.0f / s;
        ia[tid] = i1; ib[tid] = i2;

        // top-2 renormalized scores (softmax denom cancels)
        float p2   = expf(m2 - m);
        float inv12 = 1.0f / (1.0f + p2);
        out[(size_t)(tok0 + tid) * 2 + 0] = inv12;
        out[(size_t)(tok0 + tid) * 2 + 1] = p2 * inv12;
        out[(size_t)NTOK * 2 + (size_t)(tok0 + tid) * 2 + 0] = (float)i1;
        out[(size_t)NTOK * 2 + (size_t)(tok0 + tid) * 2 + 1] = (float)i2;

        float lse = m + logf(s);
        zsq = lse * lse;
#pragma unroll
        for (int o = 32; o; o >>= 1) zsq += __shfl_xor(zsq, o);  // wave-64 reduce
    }
    __syncthreads();

    // ---- per-expert block partials: lanes 0..63, one expert each ----
    if (tid < E_EXP) {
        float psum = 0.f, csum = 0.f;
        for (int t = 0; t < BT; t++) {
            psum += xs[t * LDX + tid] * rs[t];
            csum += (ia[t] == tid ? 1.f : 0.f) + (ib[t] == tid ? 1.f : 0.f);
        }
        part[bid * PART_STRIDE + tid]      = psum;
        part[bid * PART_STRIDE + 64 + tid] = csum;
        if (tid == 0) part[bid * PART_STRIDE + 128] = zsq;
    }
}

// ---------------------------------------------------------------------------
// Loss reduction: 1 block, 64 threads (one expert each)
// ---------------------------------------------------------------------------
__global__ void moe_gate_loss(const float* __restrict__ part, float* __restrict__ out)
{
    const int tid = threadIdx.x;  // 0..63
    float sp = 0.f, sc = 0.f, zp = 0.f;
    for (int b = 0; b < NBLK; b++) {
        sp += part[b * PART_STRIDE + tid];
        sc += part[b * PART_STRIDE + 64 + tid];
    }
    for (int m = 0; m < NBLK / 64; m++)
        zp += part[(tid + 64 * m) * PART_STRIDE + 128];

    const float invN = 1.0f / (float)NTOK;
    float dot = (sc * invN) * (sp * invN);   // frac_routed[e] * mean_prob[e]
#pragma unroll
    for (int o = 32; o; o >>= 1) {
        dot += __shfl_xor(dot, o);
        zp  += __shfl_xor(zp, o);
    }
    if (tid == 0)
        out[(size_t)NTOK * 4] = 0.01f * 64.0f * dot + 1e-4f * zp * invN;
}

// ---------------------------------------------------------------------------
extern "C" void kernel_launch(void* const* d_in, const int* in_sizes, int n_in,
                              void* d_out, int out_size, void* d_ws, size_t ws_size,
                              hipStream_t stream)
{
    const float* x    = (const float*)d_in[0];
    const float* gw   = (const float*)d_in[1];
    const float* bias = (const float*)d_in[2];
    float* out  = (float*)d_out;
    float* part = (float*)d_ws;   // NBLK * PART_STRIDE floats = 132 KiB

    moe_gate_main<<<NBLK, 256, 0, stream>>>(x, gw, bias, out, part);
    moe_gate_loss<<<1, 64, 0, stream>>>(part, out);
}